// Round 21
// baseline (744.732 us; speedup 1.0000x reference)
//
#include <hip/hip_runtime.h>
#include <stdint.h>

// WeightOnlyInt4Linear: y = X @ dequant(Q)^T ; M=8192, K=4096, N=11008, G=128.
// Round 21: r20 (= r13) with CORRECTED sched_group_barrier counts. r13's pins
// demanded 32 MFMA/region but regions hold 16 -> LLVM clumped the last 4
// reads at region end (uncovered LDS serve time). Fixed patterns match the
// actual contents: P1/P4 = {2M,1R}x8, P2/P3 = {4M,1R}x4, read-free = {16M}.
// Everything else byte-identical to r20.

typedef __attribute__((ext_vector_type(8))) short short8;
typedef __attribute__((ext_vector_type(4))) float float4v;
typedef __attribute__((ext_vector_type(4))) int int4v;
typedef __attribute__((ext_vector_type(2))) float float2v;
typedef __attribute__((ext_vector_type(4))) unsigned short ushort4v;

static constexpr int M_ = 8192;
static constexpr int K_ = 4096;
static constexpr int N_ = 11008;
static constexpr int NKT = K_ / 64;  // 64 K-tiles

__device__ __forceinline__ unsigned short f2bf(float f) {
    union { float f; uint32_t u; } v;
    v.f = f;
    uint32_t u = v.u;
    u += 0x7fffu + ((u >> 16) & 1u);  // RNE
    return (unsigned short)(u >> 16);
}

__device__ __forceinline__ void gload16(const void* g, void* l) {
    __builtin_amdgcn_global_load_lds(
        (const __attribute__((address_space(1))) uint32_t*)g,
        (__attribute__((address_space(3))) uint32_t*)l, 16, 0, 0);
}

// ---------------- Prepass 1: X fp32 -> bf16 ----------------
__global__ __launch_bounds__(256) void cvt_x_kernel(const float* __restrict__ X,
                                                    unsigned short* __restrict__ Xb) {
    const int i = blockIdx.x * 256 + threadIdx.x;
    const float4v a = ((const float4v*)X)[2 * (size_t)i];
    const float4v b = ((const float4v*)X)[2 * (size_t)i + 1];
    short8 o;
    #pragma unroll
    for (int j = 0; j < 4; ++j) o[j] = (short)f2bf(a[j]);
    #pragma unroll
    for (int j = 0; j < 4; ++j) o[4 + j] = (short)f2bf(b[j]);
    ((short8*)Xb)[(size_t)i] = o;
}

// ---------------- Prepass 2: W int4 codes -> bf16 ----------------
__global__ __launch_bounds__(256) void deq_w_kernel(const int* __restrict__ Q,
                                                    const float* __restrict__ SZ,
                                                    unsigned short* __restrict__ Wb) {
    const int i = blockIdx.x * 256 + threadIdx.x;  // < N*K/8
    const int n = i >> 9;
    const int c = i & 511;
    const int k0 = c * 8;
    const int g = k0 >> 7;
    const float2v sz = *(const float2v*)(SZ + ((size_t)g * N_ + n) * 2);
    const float s = sz[0], z = sz[1];
    const int4v q0 = *(const int4v*)(Q + (size_t)n * K_ + k0);
    const int4v q1 = *(const int4v*)(Q + (size_t)n * K_ + k0 + 4);
    short8 o;
    #pragma unroll
    for (int j = 0; j < 4; ++j) o[j] = (short)f2bf((float)(q0[j] - 8) * s + z);
    #pragma unroll
    for (int j = 0; j < 4; ++j) o[4 + j] = (short)f2bf((float)(q1[j] - 8) * s + z);
    ((short8*)Wb)[(size_t)i] = o;
}

// ---------------- 256x256 GEMM, SGB-pinned interleave ----------------
// LDS (bytes): A buf0 [0,32K) A buf1 [32K,64K) B buf0 [64K,96K) B buf1 [96K,128K)
// Tile: 256 rows x 64 bf16 (128 B/row); half = 128 rows = 16 KB.

#define SBAR() __builtin_amdgcn_sched_barrier(0)
#define SGB(m, n) __builtin_amdgcn_sched_group_barrier(m, n, 0)
#define VMW(n) asm volatile("s_waitcnt vmcnt(" #n ")" ::: "memory")
#define LGKM0() asm volatile("s_waitcnt lgkmcnt(0)" ::: "memory")
#define BARRIER() __builtin_amdgcn_s_barrier()
// LLVM SchedGroupMask: MFMA=0x8, DS_READ=0x100

__global__ __launch_bounds__(512, 2) void gemm_bf16_8ph(
    const unsigned short* __restrict__ Agl,  // [M][K] bf16
    const unsigned short* __restrict__ Bgl,  // [N][K] bf16
    float* __restrict__ C) {
    __shared__ alignas(16) unsigned short lds[65536];  // 128 KiB

    const int tid = threadIdx.x;
    const int lane = tid & 63;
    const int wid = tid >> 6;   // 0..7
    const int wr = wid >> 2;    // 0..1 (M sub-block within half)
    const int wc = wid & 3;     // 0..3 (N sub-block within half)

    // T1: XCD swizzle over 1376 = 8*172 blocks.
    const int bid = blockIdx.x;
    const int wg = (bid & 7) * 172 + (bid >> 3);
    const int mt = wg / 43;
    const int nt = wg % 43;
    const int row0 = mt * 256;
    const int col0 = nt * 256;

    // staging lane geometry: wave writes 8 rows x 128 B linear.
    const int r8 = lane >> 3;                // 0..7 == row&7
    const int kc = ((lane & 7) ^ r8) * 8;    // inverse-swizzled global k-elem offset

    // ds_read lane geometry: read row&7 = l15&7.
    const int l15 = lane & 15;
    const int k0o = ((lane >> 4) * 16) ^ ((l15 & 7) << 4);
    const int k1o = k0o ^ 64;
    const int aK0 = (wr * 64 + l15) * 128 + k0o;          // A ds_read bases
    const int aK1 = (wr * 64 + l15) * 128 + k1o;
    const int bK0 = 65536 + (wc * 32 + l15) * 128 + k0o;  // B bases (+64K bias)
    const int bK1 = 65536 + (wc * 32 + l15) * 128 + k1o;
    const char* ldsB = (const char*)lds;
    unsigned short* ldsU = lds;
    const char* AglB = (const char*)Agl;
    const char* BglB = (const char*)Bgl;

    // Persistent 32-bit staging byte-offsets, one per stream [h][i]; +128 B/use.
    uint32_t sA[2][2], sB[2][2];
    #pragma unroll
    for (int h = 0; h < 2; ++h)
        #pragma unroll
        for (int i = 0; i < 2; ++i) {
            sA[h][i] = (uint32_t)(row0 + h * 128 + (wid * 2 + i) * 8 + r8) * (K_ * 2)
                       + (uint32_t)kc * 2;
            sB[h][i] = (uint32_t)(col0 + h * 128 + (wid * 2 + i) * 8 + r8) * (K_ * 2)
                       + (uint32_t)kc * 2;
        }

    auto gA = [&](uint32_t& off, int b, int h, int i) {
        gload16(AglB + off, ldsU + b * 16384 + (h * 128 + (wid * 2 + i) * 8) * 64);
        off += 128;
    };
    auto gB = [&](uint32_t& off, int b, int h, int i) {
        gload16(BglB + off, ldsU + 32768 + b * 16384 + (h * 128 + (wid * 2 + i) * 8) * 64);
        off += 128;
    };

    float4v acc[8][4] = {};
    short8 a0[4][2], a1[4][2];  // A h0/h1 fragments (persist across tiles)
    short8 b0[2][2], b1[2][2];  // B h0/h1 fragments

#define MMA2(MH, NH, I, J, A, B)                                              \
    acc[(MH)*4+(I)][(NH)*2+(J)] = __builtin_amdgcn_mfma_f32_16x16x32_bf16(    \
        A[I][0], B[J][0], acc[(MH)*4+(I)][(NH)*2+(J)], 0, 0, 0);              \
    acc[(MH)*4+(I)][(NH)*2+(J)] = __builtin_amdgcn_mfma_f32_16x16x32_bf16(    \
        A[I][1], B[J][1], acc[(MH)*4+(I)][(NH)*2+(J)], 0, 0, 0);
#define RDA(DST, BASE, I)                                                     \
    DST[I][0] = *(const short8*)(ldsB + (BASE) + (I)*2048 + aK0);             \
    DST[I][1] = *(const short8*)(ldsB + (BASE) + (I)*2048 + aK1);
#define RDB(DST, BASE, J)                                                     \
    DST[J][0] = *(const short8*)(ldsB + (BASE) + (J)*2048 + bK0);             \
    DST[J][1] = *(const short8*)(ldsB + (BASE) + (J)*2048 + bK1);
// SGB pin patterns — counts match region contents EXACTLY (16 MFMA/region).
#define PIN_16M_8R()                                                          \
    SGB(0x8, 2); SGB(0x100, 1); SGB(0x8, 2); SGB(0x100, 1);                   \
    SGB(0x8, 2); SGB(0x100, 1); SGB(0x8, 2); SGB(0x100, 1);                   \
    SGB(0x8, 2); SGB(0x100, 1); SGB(0x8, 2); SGB(0x100, 1);                   \
    SGB(0x8, 2); SGB(0x100, 1); SGB(0x8, 2); SGB(0x100, 1);
#define PIN_16M_4R()                                                          \
    SGB(0x8, 4); SGB(0x100, 1); SGB(0x8, 4); SGB(0x100, 1);                   \
    SGB(0x8, 4); SGB(0x100, 1); SGB(0x8, 4); SGB(0x100, 1);
#define PIN_16M()  SGB(0x8, 16);

    // Prologue: tile 0 -> buf0 (A0,A1,B0,B1) + A0(1) -> buf1; VMW(2) leaves
    // the A0(1) pair in flight; read a0,b0 of tile 0.
    gA(sA[0][0], 0, 0, 0); gA(sA[0][1], 0, 0, 1);
    gA(sA[1][0], 0, 1, 0); gA(sA[1][1], 0, 1, 1);
    gB(sB[0][0], 0, 0, 0); gB(sB[0][1], 0, 0, 1);
    gB(sB[1][0], 0, 1, 0); gB(sB[1][1], 0, 1, 1);
    gA(sA[0][0], 1, 0, 0); gA(sA[0][1], 1, 0, 1);  // A0(1) -> buf1, stays in flight
    VMW(2);
    BARRIER(); SBAR();
    RDA(a0, 0, 0) RDA(a0, 0, 1) RDA(a0, 0, 2) RDA(a0, 0, 3)
    RDB(b0, 0, 0) RDB(b0, 0, 1)
    LGKM0(); SBAR();

    // Per tile t (BUF=t&1):
    // P1: stage S1->BUF^1 ; mma<0,0>(a0,b0) ∥ read a1<-BUF      [{2M,1R}x8]
    // P2: stage S2->BUF^1 ; mma<1,0>(a1,b0) ∥ read b1<-BUF      [{4M,1R}x4]
    // MID: stage S3->BUF ; VMW(MIDW) ; BAR
    // P3: mma<0,1>(a0,b1) ∥ read b0'<-BUF^1 (WAR safe)          [{4M,1R}x4]
    // P4: mma<1,1>(a1,b1) ∥ read a0'<-BUF^1                     [{2M,1R}x8]
    // END: VMW(ENDW) ; BAR ; lgkmcnt(0)
#define KTILE(BUF, DN, DN2, MIDW, ENDW, DOEND)                                \
    {                                                                         \
        constexpr int CB = (BUF) * 32768;                                     \
        constexpr int NB = ((BUF) ^ 1) * 32768;                               \
        /* ---- P1 ---- */                                                    \
        if (DN) {                                                             \
            gA(sA[1][0], (BUF) ^ 1, 1, 0); gA(sA[1][1], (BUF) ^ 1, 1, 1);     \
            gB(sB[0][0], (BUF) ^ 1, 0, 0); gB(sB[0][1], (BUF) ^ 1, 0, 1);     \
        }                                                                     \
        __builtin_amdgcn_s_setprio(1);                                        \
        MMA2(0, 0, 0, 0, a0, b0) RDA(a1, CB + 16384, 0)                       \
        MMA2(0, 0, 0, 1, a0, b0) RDA(a1, CB + 16384, 1)                       \
        MMA2(0, 0, 1, 0, a0, b0) RDA(a1, CB + 16384, 2)                       \
        MMA2(0, 0, 1, 1, a0, b0) RDA(a1, CB + 16384, 3)                       \
        MMA2(0, 0, 2, 0, a0, b0) MMA2(0, 0, 2, 1, a0, b0)                     \
        MMA2(0, 0, 3, 0, a0, b0) MMA2(0, 0, 3, 1, a0, b0)                     \
        if (DN) { PIN_16M_8R() } else { PIN_16M() }                           \
        __builtin_amdgcn_s_setprio(0);                                        \
        LGKM0(); SBAR();                                                      \
        /* ---- P2 ---- */                                                    \
        if (DN) { gB(sB[1][0], (BUF) ^ 1, 1, 0); gB(sB[1][1], (BUF) ^ 1, 1, 1); } \
        __builtin_amdgcn_s_setprio(1);                                        \
        MMA2(1, 0, 0, 0, a1, b0) RDB(b1, CB + 16384, 0)                       \
        MMA2(1, 0, 0, 1, a1, b0) RDB(b1, CB + 16384, 1)                       \
        MMA2(1, 0, 1, 0, a1, b0) MMA2(1, 0, 1, 1, a1, b0)                     \
        MMA2(1, 0, 2, 0, a1, b0) MMA2(1, 0, 2, 1, a1, b0)                     \
        MMA2(1, 0, 3, 0, a1, b0) MMA2(1, 0, 3, 1, a1, b0)                     \
        PIN_16M_4R()                                                          \
        __builtin_amdgcn_s_setprio(0);                                        \
        LGKM0(); SBAR();                                                      \
        /* ---- MID sync ---- */                                              \
        if (DN2) { gA(sA[0][0], BUF, 0, 0); gA(sA[0][1], BUF, 0, 1); }        \
        VMW(MIDW);                                                            \
        BARRIER(); SBAR();                                                    \
        /* ---- P3 ---- */                                                    \
        __builtin_amdgcn_s_setprio(1);                                        \
        MMA2(0, 1, 0, 0, a0, b1)                                              \
        if (DN) { RDB(b0, NB, 0) }                                            \
        MMA2(0, 1, 0, 1, a0, b1)                                              \
        if (DN) { RDB(b0, NB, 1) }                                            \
        MMA2(0, 1, 1, 0, a0, b1) MMA2(0, 1, 1, 1, a0, b1)                     \
        MMA2(0, 1, 2, 0, a0, b1) MMA2(0, 1, 2, 1, a0, b1)                     \
        MMA2(0, 1, 3, 0, a0, b1) MMA2(0, 1, 3, 1, a0, b1)                     \
        if (DN) { PIN_16M_4R() } else { PIN_16M() }                           \
        __builtin_amdgcn_s_setprio(0);                                        \
        SBAR();                                                               \
        /* ---- P4 ---- */                                                    \
        __builtin_amdgcn_s_setprio(1);                                        \
        MMA2(1, 1, 0, 0, a1, b1)                                              \
        if (DN) { RDA(a0, NB, 0) }                                            \
        MMA2(1, 1, 0, 1, a1, b1)                                              \
        if (DN) { RDA(a0, NB, 1) }                                            \
        MMA2(1, 1, 1, 0, a1, b1)                                              \
        if (DN) { RDA(a0, NB, 2) }                                            \
        MMA2(1, 1, 1, 1, a1, b1)                                              \
        if (DN) { RDA(a0, NB, 3) }                                            \
        MMA2(1, 1, 2, 0, a1, b1) MMA2(1, 1, 2, 1, a1, b1)                     \
        MMA2(1, 1, 3, 0, a1, b1) MMA2(1, 1, 3, 1, a1, b1)                     \
        if (DN) { PIN_16M_8R() } else { PIN_16M() }                           \
        __builtin_amdgcn_s_setprio(0);                                        \
        if (DOEND) {                                                          \
            VMW(ENDW);                                                        \
            BARRIER(); SBAR();                                                \
            LGKM0(); SBAR();                                                  \
        }                                                                     \
    }

    for (int t2 = 0; t2 < NKT - 2; t2 += 2) {
        KTILE(0, 1, 1, 4, 2, 1);
        KTILE(1, 1, 1, 4, 2, 1);
    }
    KTILE(0, 1, 0, 2, 0, 1);  // t=62: no S3; MID drains S3(61)+S1(62); END drains S2(62)
    KTILE(1, 0, 0, 0, 0, 0);  // t=63: pure compute
#undef KTILE
#undef MMA2
#undef RDA
#undef RDB

    // Epilogue: D map col=lane&15, row=(lane>>4)*4+j (m89-verified).
    const int lrow = (lane >> 4) * 4;
    #pragma unroll
    for (int mf = 0; mf < 8; ++mf)
        #pragma unroll
        for (int nf = 0; nf < 4; ++nf)
            #pragma unroll
            for (int j = 0; j < 4; ++j) {
                const int r = row0 + (mf >> 2) * 128 + wr * 64 + (mf & 3) * 16 + lrow + j;
                const int c = col0 + (nf >> 1) * 128 + wc * 32 + (nf & 1) * 16 + l15;
                C[(size_t)r * N_ + c] = acc[mf][nf][j];
            }
}

// ---------------- Fallback: round-1 fused kernel ----------------
static constexpr int LDSS = 40;

__global__ __launch_bounds__(256, 2) void w4_gemm_fused(
    const float* __restrict__ X, const int* __restrict__ Q,
    const float* __restrict__ SZ, float* __restrict__ C) {
    __shared__ alignas(16) unsigned short As[128 * LDSS];
    __shared__ alignas(16) unsigned short Ws[128 * LDSS];
    const int tid = threadIdx.x;
    const int lane = tid & 63;
    const int wid = tid >> 6;
    const int wrr = wid >> 1;
    const int wcc = wid & 1;
    const int row0 = blockIdx.x * 128;
    const int col0 = blockIdx.y * 128;
    float4v acc[4][4] = {};
    float4v a_reg[4];
    int4v q_reg[4];
    float2v sz_reg[4];

    auto load_tile = [&](int kb) {
        const int g = kb >> 7;
        #pragma unroll
        for (int i = 0; i < 4; ++i) {
            const int idx = tid + 256 * i;
            const int r = idx >> 3;
            const int v = idx & 7;
            a_reg[i] = *(const float4v*)(X + (size_t)(row0 + r) * K_ + kb + v * 4);
            q_reg[i] = *(const int4v*)(Q + (size_t)(col0 + r) * K_ + kb + v * 4);
            sz_reg[i] = *(const float2v*)(SZ + ((size_t)g * N_ + (col0 + r)) * 2);
        }
    };
    auto write_tile = [&]() {
        #pragma unroll
        for (int i = 0; i < 4; ++i) {
            const int idx = tid + 256 * i;
            const int r = idx >> 3;
            const int v = idx & 7;
            ushort4v ab, wb;
            #pragma unroll
            for (int j = 0; j < 4; ++j) ab[j] = f2bf(a_reg[i][j]);
            const float s = sz_reg[i][0];
            const float z = sz_reg[i][1];
            #pragma unroll
            for (int j = 0; j < 4; ++j) wb[j] = f2bf((float)(q_reg[i][j] - 8) * s + z);
            *(ushort4v*)(&As[r * LDSS + v * 4]) = ab;
            *(ushort4v*)(&Ws[r * LDSS + v * 4]) = wb;
        }
    };
    auto compute = [&]() {
        const int lr = lane & 15;
        const int lgg = lane >> 4;
        short8 af[4], bf[4];
        #pragma unroll
        for (int mf = 0; mf < 4; ++mf)
            af[mf] = *(const short8*)(&As[(wrr * 64 + mf * 16 + lr) * LDSS + lgg * 8]);
        #pragma unroll
        for (int nf = 0; nf < 4; ++nf)
            bf[nf] = *(const short8*)(&Ws[(wcc * 64 + nf * 16 + lr) * LDSS + lgg * 8]);
        #pragma unroll
        for (int mf = 0; mf < 4; ++mf)
            #pragma unroll
            for (int nf = 0; nf < 4; ++nf)
                acc[mf][nf] = __builtin_amdgcn_mfma_f32_16x16x32_bf16(
                    af[mf], bf[nf], acc[mf][nf], 0, 0, 0);
    };

    load_tile(0);
    for (int kb = 0; kb < K_; kb += 32) {
        __syncthreads();
        write_tile();
        __syncthreads();
        if (kb + 32 < K_) load_tile(kb + 32);
        compute();
    }
    const int lr = lane & 15;
    const int lgg = lane >> 4;
    #pragma unroll
    for (int mf = 0; mf < 4; ++mf)
        #pragma unroll
        for (int nf = 0; nf < 4; ++nf)
            #pragma unroll
            for (int j = 0; j < 4; ++j) {
                const int r = row0 + wrr * 64 + mf * 16 + lgg * 4 + j;
                const int c = col0 + wcc * 64 + nf * 16 + lr;
                C[(size_t)r * N_ + c] = acc[mf][nf][j];
            }
}

extern "C" void kernel_launch(void* const* d_in, const int* in_sizes, int n_in,
                              void* d_out, int out_size, void* d_ws, size_t ws_size,
                              hipStream_t stream) {
    const float* X  = (const float*)d_in[0];
    const int*   Q  = (const int*)d_in[1];
    const float* SZ = (const float*)d_in[2];
    float* C = (float*)d_out;

    const size_t xb_bytes = (size_t)M_ * K_ * 2;
    const size_t wb_bytes = (size_t)N_ * K_ * 2;
    if (ws_size >= xb_bytes + wb_bytes) {
        unsigned short* Xb = (unsigned short*)d_ws;
        unsigned short* Wb = (unsigned short*)((char*)d_ws + xb_bytes);
        cvt_x_kernel<<<(M_ * (K_ / 8)) / 256, 256, 0, stream>>>(X, Xb);
        deq_w_kernel<<<(N_ * (K_ / 8)) / 256, 256, 0, stream>>>(Q, SZ, Wb);
        gemm_bf16_8ph<<<dim3(1376), dim3(512), 0, stream>>>(Xb, Wb, C);
    } else {
        dim3 grid(M_ / 128, N_ / 128);
        w4_gemm_fused<<<grid, dim3(256), 0, stream>>>(X, Q, SZ, C);
    }
}